// Round 8
// baseline (393.367 us; speedup 1.0000x reference)
//
#include <hip/hip_runtime.h>
#include <hip/hip_bf16.h>
#include <math.h>

typedef __hip_bfloat16 bf16;
typedef __attribute__((ext_vector_type(8))) short short8;
typedef __attribute__((ext_vector_type(4))) float f32x4;

#define MFMA16(A, B, C) __builtin_amdgcn_mfma_f32_16x16x32_bf16((A), (B), (C), 0, 0, 0)
#define NEG_BIG (-1e30f)

// fp32 -> bf16 round-to-nearest-even via bit ops
static __device__ __forceinline__ unsigned short f32_to_bf16_rne(float f) {
    unsigned int u = __float_as_uint(f);
    unsigned int rnd = 0x7FFFu + ((u >> 16) & 1u);
    return (unsigned short)((u + rnd) >> 16);
}

// ---------------------------------------------------------------------------
// Kernel 0a: dtype probe (bf16 vs fp32 input bits) -> flag in ws.
// ---------------------------------------------------------------------------
__global__ void dtype_probe(const unsigned short* __restrict__ x,
                            unsigned int* __restrict__ flag)
{
    __shared__ int cnt_s[256];
    const int tid = threadIdx.x;
    int c = 0;
    for (int i = tid; i < 4096; i += 256) {
        int e = (x[i] >> 7) & 0xFF;
        if (e >= 133) ++c;
    }
    cnt_s[tid] = c;
    __syncthreads();
    for (int off = 128; off > 0; off >>= 1) {
        if (tid < off) cnt_s[tid] += cnt_s[tid + off];
        __syncthreads();
    }
    if (tid == 0) flag[0] = (cnt_s[0] > 32) ? 1u : 0u;  // 1 = inputs are fp32
}

// ---------------------------------------------------------------------------
// Kernel 0b: canonical bf16 copies of all 5 inputs in ONE launch.
// ---------------------------------------------------------------------------
__global__ __launch_bounds__(256) void convert_all(
    const void* __restrict__ xs, const void* __restrict__ wq,
    const void* __restrict__ wk, const void* __restrict__ wv,
    const void* __restrict__ wo,
    unsigned int* __restrict__ Xc, unsigned int* __restrict__ Wqc,
    unsigned int* __restrict__ Wkc, unsigned int* __restrict__ Wvc,
    unsigned int* __restrict__ Woc,
    const unsigned int* __restrict__ flag)
{
    int i = blockIdx.x * 256 + threadIdx.x;  // 0 .. 4194303
    const void* src;
    unsigned int* dst;
    int off;
    if (i < 2097152) { src = xs; dst = Xc; off = i; }
    else {
        int j = i - 2097152;
        int t = j >> 19;          // 0..3
        off = j & 524287;
        src = (t == 0) ? wq : (t == 1) ? wk : (t == 2) ? wv : wo;
        dst = (t == 0) ? Wqc : (t == 1) ? Wkc : (t == 2) ? Wvc : Woc;
    }
    if (flag[0] == 0u) {
        dst[off] = ((const unsigned int*)src)[off];
    } else {
        const float* f = (const float*)src;
        unsigned int lo = f32_to_bf16_rne(f[2 * off]);
        unsigned int hi = f32_to_bf16_rne(f[2 * off + 1]);
        dst[off] = (hi << 16) | lo;
    }
}

// ---------------------------------------------------------------------------
// Kernel 1: QKV projection GEMM (C = X * W^T) with fused RoPE epilogue.
// Register-prefetch pipeline; V written TRANSPOSED [b,h,d,s] via LDS.
// ---------------------------------------------------------------------------
__global__ __launch_bounds__(256) void gemm_qkv_rope(
    const bf16* __restrict__ X,
    const bf16* __restrict__ Wq, const bf16* __restrict__ Wk,
    const bf16* __restrict__ Wv,
    const int* __restrict__ pos,
    bf16* __restrict__ Qb, bf16* __restrict__ Kb, bf16* __restrict__ Vt)
{
    __shared__ __align__(16) short Xs[64 * 40];
    __shared__ __align__(16) short Ws[64 * 40];
    __shared__ __align__(16) short Ts[64 * 72];   // V transpose staging

    const int m0   = blockIdx.x * 64;
    const int wsel = blockIdx.y >> 4;            // 0=Q, 1=K, 2=V
    const int n0   = (blockIdx.y & 15) * 64;
    const bf16* W  = (wsel == 0) ? Wq : (wsel == 1) ? Wk : Wv;

    const int tid  = threadIdx.x;
    const int lane = tid & 63;
    const int wave = tid >> 6;
    const int wr   = wave >> 1, wc = wave & 1;
    const int srow = tid >> 2;
    const int sseg = tid & 3;
    const int fr   = lane & 15;
    const int fq   = lane >> 4;

    const bf16* Xrow = X + (m0 + srow) * 1024 + sseg * 8;
    const bf16* Wrow = W + (n0 + srow) * 1024 + sseg * 8;

    f32x4 acc00 = {0.f,0.f,0.f,0.f}, acc01 = {0.f,0.f,0.f,0.f};
    f32x4 acc10 = {0.f,0.f,0.f,0.f}, acc11 = {0.f,0.f,0.f,0.f};

    short8 pxa = *(const short8*)(Xrow);   // prefetch k0 = 0
    short8 pwb = *(const short8*)(Wrow);

    for (int k0 = 0; k0 < 1024; k0 += 32) {
        __syncthreads();
        *(short8*)&Xs[srow * 40 + sseg * 8] = pxa;
        *(short8*)&Ws[srow * 40 + sseg * 8] = pwb;
        __syncthreads();
        if (k0 + 32 < 1024) {               // prefetch next tile (overlaps MFMA)
            pxa = *(const short8*)(Xrow + k0 + 32);
            pwb = *(const short8*)(Wrow + k0 + 32);
        }

        short8 a0 = *(const short8*)&Xs[(wr * 32 +      fr) * 40 + fq * 8];
        short8 a1 = *(const short8*)&Xs[(wr * 32 + 16 + fr) * 40 + fq * 8];
        short8 b0 = *(const short8*)&Ws[(wc * 32 +      fr) * 40 + fq * 8];
        short8 b1 = *(const short8*)&Ws[(wc * 32 + 16 + fr) * 40 + fq * 8];
        acc00 = MFMA16(a0, b0, acc00);
        acc01 = MFMA16(a0, b1, acc01);
        acc10 = MFMA16(a1, b0, acc10);
        acc11 = MFMA16(a1, b1, acc11);
    }

    const int bb = m0 >> 11;
    const int s0 = m0 & 2047;
    const int hh = n0 >> 6;

    if (wsel < 2) {
        for (int i = 0; i < 2; ++i)
            for (int j = 0; j < 2; ++j) {
                f32x4 a = (i == 0) ? ((j == 0) ? acc00 : acc01)
                                   : ((j == 0) ? acc10 : acc11);
                for (int r = 0; r < 4; ++r) {
                    int s = s0 + wr * 32 + i * 16 + fq * 4 + r;
                    int d = wc * 32 + j * 16 + fr;
                    float v = a[r];
                    float partner = __shfl_xor(v, 1);
                    int   p    = d >> 1;
                    float freq = __expf((float)p * -0.28782313662425575f);
                    float ang  = (float)pos[s] * freq;
                    float sn, c;
                    sincosf(ang, &sn, &c);
                    float outv = ((d & 1) == 0) ? (c * v - sn * partner)
                                                : (sn * partner + c * v);
                    bf16* dstb = (wsel == 0) ? Qb : Kb;
                    dstb[((bb * 16 + hh) * 2048 + s) * 64 + d] = __float2bfloat16(outv);
                }
            }
    } else {
        for (int i = 0; i < 2; ++i)
            for (int j = 0; j < 2; ++j) {
                f32x4 a = (i == 0) ? ((j == 0) ? acc00 : acc01)
                                   : ((j == 0) ? acc10 : acc11);
                for (int r = 0; r < 4; ++r) {
                    int ls = wr * 32 + i * 16 + fq * 4 + r;   // local s
                    int ld = wc * 32 + j * 16 + fr;           // local d
                    bf16 hv = __float2bfloat16(a[r]);
                    Ts[ld * 72 + ls] = *(short*)&hv;
                }
            }
        __syncthreads();
        int dd = tid >> 2;
        int sc = (tid & 3) * 16;
        short8 t0 = *(const short8*)&Ts[dd * 72 + sc];
        short8 t1 = *(const short8*)&Ts[dd * 72 + sc + 8];
        bf16* vrow = Vt + ((bb * 16 + hh) * 64 + dd) * 2048 + s0 + sc;
        *(short8*)(vrow)     = t0;
        *(short8*)(vrow + 8) = t1;
    }
}

// ---------------------------------------------------------------------------
// Kernel 2: causal flash attention, MFMA bf16, BARRIER-FREE.
// grid = (32 qt, 16 h, 2 b), block = 256 (4 fully independent waves).
// K and V^T fragments load DIRECTLY from global (L2-resident, no LDS
// staging, no __syncthreads). Only P round-trips through a wave-private
// LDS buffer (in-wave lgkmcnt ordering, no barrier needed).
// ---------------------------------------------------------------------------
#define FS 72

__global__ __launch_bounds__(256) void flash_attn(
    const bf16* __restrict__ Qb, const bf16* __restrict__ Kb,
    const bf16* __restrict__ Vt, bf16* __restrict__ ctx)
{
    const int qt = 31 - blockIdx.x;   // long blocks dispatch first
    const int h = blockIdx.y, b = blockIdx.z;
    const int bh = b * 16 + h;

    __shared__ __align__(16) short Ps[4][16 * FS];   // per-wave P buffer

    const int tid  = threadIdx.x;
    const int lane = tid & 63;
    const int wave = tid >> 6;
    const int m = lane & 15;          // fragment row/col
    const int q = lane >> 4;          // quad

    const f32x4 ZERO4 = {0.f, 0.f, 0.f, 0.f};

    // Q fragments, persistent: A[m][k=q*8+j], rows qt*64 + wave*16 + m
    const bf16* Qp = Qb + (bh * 2048 + qt * 64 + wave * 16 + m) * 64;
    short8 qf0 = *(const short8*)(Qp + q * 8);
    short8 qf1 = *(const short8*)(Qp + 32 + q * 8);

    // fragment base pointers (element offsets added per tile)
    const bf16* Kf = Kb + (bh * 2048 + m) * 64 + q * 8;   // +kt*4096 +nb*1024 (+32)
    const bf16* Vf = Vt + (bh * 64 + m) * 2048 + q * 8;   // +nb*32768 +kt*64 (+32)

    f32x4 oacc[4];
    for (int nb = 0; nb < 4; ++nb) oacc[nb] = ZERO4;
    float mi[4], li[4];
    for (int r = 0; r < 4; ++r) { mi[r] = NEG_BIG; li[r] = 0.f; }

    // prefetch K tile 0 fragments
    short8 kf[4][2];
    for (int nb = 0; nb < 4; ++nb) {
        kf[nb][0] = *(const short8*)(Kf + nb * 1024);
        kf[nb][1] = *(const short8*)(Kf + nb * 1024 + 32);
    }

    for (int kt = 0; kt <= qt; ++kt) {
        // ---- S = Q K^T  (C layout: row = q*4+r, col = nb*16+m) ----
        f32x4 sacc[4];
        for (int nb = 0; nb < 4; ++nb) {
            f32x4 z = ZERO4;
            z = MFMA16(qf0, kf[nb][0], z);
            z = MFMA16(qf1, kf[nb][1], z);
            sacc[nb] = z;
        }

        // ---- issue V fragment loads now; consumed after softmax ----
        short8 vf[4][2];
        for (int nb = 0; nb < 4; ++nb) {
            vf[nb][0] = *(const short8*)(Vf + nb * 32768 + kt * 64);
            vf[nb][1] = *(const short8*)(Vf + nb * 32768 + kt * 64 + 32);
        }

        // ---- prefetch K fragments for next tile (clamped re-read on last) ----
        const int ktn = (kt < qt) ? kt + 1 : qt;
        for (int nb = 0; nb < 4; ++nb) {
            kf[nb][0] = *(const short8*)(Kf + ktn * 4096 + nb * 1024);
            kf[nb][1] = *(const short8*)(Kf + ktn * 4096 + nb * 1024 + 32);
        }

        // ---- scale + causal mask (diagonal tile only) ----
        const bool diag = (kt == qt);
        for (int nb = 0; nb < 4; ++nb)
            for (int r = 0; r < 4; ++r) {
                float sv = sacc[nb][r] * 0.125f;
                if (diag && (nb * 16 + m) > (wave * 16 + q * 4 + r))
                    sv = NEG_BIG;
                sacc[nb][r] = sv;
            }

        // ---- online softmax (16-lane quad shuffles; lane's rows = q*4+r) ----
        float mnew[4], alpha[4];
        for (int r = 0; r < 4; ++r) {
            float rm = fmaxf(fmaxf(sacc[0][r], sacc[1][r]),
                             fmaxf(sacc[2][r], sacc[3][r]));
            for (int off = 1; off < 16; off <<= 1)
                rm = fmaxf(rm, __shfl_xor(rm, off));
            mnew[r]  = fmaxf(mi[r], rm);
            alpha[r] = __expf(fmaxf(mi[r] - mnew[r], -80.f));
            mi[r]    = mnew[r];
        }
        for (int r = 0; r < 4; ++r) {
            float acc = 0.f;
            for (int nb = 0; nb < 4; ++nb) {
                float p = __expf(fmaxf(sacc[nb][r] - mnew[r], -80.f));
                sacc[nb][r] = p;
                acc += p;
            }
            for (int off = 1; off < 16; off <<= 1)
                acc += __shfl_xor(acc, off);
            li[r] = li[r] * alpha[r] + acc;
            for (int nb = 0; nb < 4; ++nb) oacc[nb][r] *= alpha[r];
        }

        // ---- P (C layout) -> wave-private LDS -> A-frag layout ----
        for (int nb = 0; nb < 4; ++nb)
            for (int r = 0; r < 4; ++r) {
                bf16 hv = __float2bfloat16(sacc[nb][r]);
                Ps[wave][(q * 4 + r) * FS + nb * 16 + m] = *(short*)&hv;
            }
        short8 pa0 = *(const short8*)&Ps[wave][m * FS + q * 8];
        short8 pa1 = *(const short8*)&Ps[wave][m * FS + 32 + q * 8];

        // ---- O += P V  (B-frag rows = d, k = key) ----
        for (int nb = 0; nb < 4; ++nb) {
            oacc[nb] = MFMA16(pa0, vf[nb][0], oacc[nb]);
            oacc[nb] = MFMA16(pa1, vf[nb][1], oacc[nb]);
        }
    }

    // ---- normalize + write ctx [b, s, h*64+d] ----
    for (int r = 0; r < 4; ++r) {
        float inv = 1.f / li[r];
        int srowg = qt * 64 + wave * 16 + q * 4 + r;
        for (int nb = 0; nb < 4; ++nb)
            ctx[(b * 2048 + srowg) * 1024 + h * 64 + nb * 16 + m] =
                __float2bfloat16(oacc[nb][r] * inv);
    }
}

// ---------------------------------------------------------------------------
// Kernel 3: output projection (out = ctx * Wo^T), prefetch pipeline.
// ---------------------------------------------------------------------------
__global__ __launch_bounds__(256) void gemm_out(
    const bf16* __restrict__ A, const bf16* __restrict__ W,
    void* __restrict__ out, const unsigned int* __restrict__ flag)
{
    __shared__ __align__(16) short As[64 * 40];
    __shared__ __align__(16) short Ws[64 * 40];

    const int m0 = blockIdx.x * 64;
    const int n0 = blockIdx.y * 64;
    const int tid  = threadIdx.x;
    const int lane = tid & 63;
    const int wave = tid >> 6;
    const int wr = wave >> 1, wc = wave & 1;
    const int srow = tid >> 2, sseg = tid & 3;
    const int fr = lane & 15, fq = lane >> 4;
    const unsigned int fl = flag[0];

    const bf16* Arow = A + (m0 + srow) * 1024 + sseg * 8;
    const bf16* Wrow = W + (n0 + srow) * 1024 + sseg * 8;

    f32x4 acc00 = {0.f,0.f,0.f,0.f}, acc01 = {0.f,0.f,0.f,0.f};
    f32x4 acc10 = {0.f,0.f,0.f,0.f}, acc11 = {0.f,0.f,0.f,0.f};

    short8 paa = *(const short8*)(Arow);
    short8 pwb = *(const short8*)(Wrow);

    for (int k0 = 0; k0 < 1024; k0 += 32) {
        __syncthreads();
        *(short8*)&As[srow * 40 + sseg * 8] = paa;
        *(short8*)&Ws[srow * 40 + sseg * 8] = pwb;
        __syncthreads();
        if (k0 + 32 < 1024) {
            paa = *(const short8*)(Arow + k0 + 32);
            pwb = *(const short8*)(Wrow + k0 + 32);
        }
        short8 a0 = *(const short8*)&As[(wr * 32 +      fr) * 40 + fq * 8];
        short8 a1 = *(const short8*)&As[(wr * 32 + 16 + fr) * 40 + fq * 8];
        short8 b0 = *(const short8*)&Ws[(wc * 32 +      fr) * 40 + fq * 8];
        short8 b1 = *(const short8*)&Ws[(wc * 32 + 16 + fr) * 40 + fq * 8];
        acc00 = MFMA16(a0, b0, acc00);
        acc01 = MFMA16(a0, b1, acc01);
        acc10 = MFMA16(a1, b0, acc10);
        acc11 = MFMA16(a1, b1, acc11);
    }

    for (int i = 0; i < 2; ++i)
        for (int j = 0; j < 2; ++j) {
            f32x4 a = (i == 0) ? ((j == 0) ? acc00 : acc01)
                               : ((j == 0) ? acc10 : acc11);
            for (int r = 0; r < 4; ++r) {
                int gm = m0 + wr * 32 + i * 16 + fq * 4 + r;
                int gn = n0 + wc * 32 + j * 16 + fr;
                int idx = gm * 1024 + gn;
                if (fl == 0u) ((bf16*)out)[idx]  = __float2bfloat16(a[r]);
                else          ((float*)out)[idx] = a[r];
            }
        }
}

// ---------------------------------------------------------------------------
extern "C" void kernel_launch(void* const* d_in, const int* in_sizes, int n_in,
                              void* d_out, int out_size, void* d_ws, size_t ws_size,
                              hipStream_t stream)
{
    const void* x_raw  = d_in[0];
    const void* Wq_raw = d_in[1];
    const void* Wk_raw = d_in[2];
    const void* Wv_raw = d_in[3];
    const void* Wo_raw = d_in[4];
    const int*  pos    = (const int*)d_in[5];

    char* ws = (char*)d_ws;
    unsigned int* flag = (unsigned int*)ws;                   // 256 B
    bf16* Xc  = (bf16*)(ws + 256);                            // 8 MB
    bf16* Wqc = (bf16*)(ws + 256 + 8388608);                  // 2 MB each
    bf16* Wkc = (bf16*)(ws + 256 + 8388608 + 2097152);
    bf16* Wvc = (bf16*)(ws + 256 + 8388608 + 2 * 2097152);
    bf16* Woc = (bf16*)(ws + 256 + 8388608 + 3 * 2097152);
    bf16* Qb  = (bf16*)(ws + 256 + 8388608 + 4 * 2097152);    // 8 MB each
    bf16* Kb  = Qb + 4194304;
    bf16* Vt  = Kb + 4194304;
    bf16* ctx = Vt + 4194304;

    dtype_probe<<<1, 256, 0, stream>>>((const unsigned short*)x_raw, flag);

    convert_all<<<16384, 256, 0, stream>>>(
        x_raw, Wq_raw, Wk_raw, Wv_raw, Wo_raw,
        (unsigned int*)Xc, (unsigned int*)Wqc, (unsigned int*)Wkc,
        (unsigned int*)Wvc, (unsigned int*)Woc, flag);

    gemm_qkv_rope<<<dim3(64, 48), 256, 0, stream>>>(Xc, Wqc, Wkc, Wvc, pos, Qb, Kb, Vt);
    flash_attn<<<dim3(32, 16, 2), 256, 0, stream>>>(Qb, Kb, Vt, ctx);
    gemm_out<<<dim3(64, 16), 256, 0, stream>>>(ctx, Woc, d_out, flag);
}

// Round 9
// 265.688 us; speedup vs baseline: 1.4806x; 1.4806x over previous
//
#include <hip/hip_runtime.h>
#include <hip/hip_bf16.h>
#include <math.h>

typedef __hip_bfloat16 bf16;
typedef __attribute__((ext_vector_type(8))) short short8;
typedef __attribute__((ext_vector_type(4))) float f32x4;

#define MFMA16(A, B, C) __builtin_amdgcn_mfma_f32_16x16x32_bf16((A), (B), (C), 0, 0, 0)
#define NEG_BIG (-1e30f)

// DPP row_ror rotate within 16-lane rows (VALU pipe — NOT LDS, unlike __shfl)
#define DPP_F(x, ctrl) \
    __int_as_float(__builtin_amdgcn_update_dpp(0, __float_as_int(x), (ctrl), 0xf, 0xf, false))

static __device__ __forceinline__ float rowsum16(float x) {
    x += DPP_F(x, 0x121);   // ror:1
    x += DPP_F(x, 0x122);   // ror:2
    x += DPP_F(x, 0x124);   // ror:4
    x += DPP_F(x, 0x128);   // ror:8
    return x;
}
static __device__ __forceinline__ float rowmax16(float x) {
    x = fmaxf(x, DPP_F(x, 0x121));
    x = fmaxf(x, DPP_F(x, 0x122));
    x = fmaxf(x, DPP_F(x, 0x124));
    x = fmaxf(x, DPP_F(x, 0x128));
    return x;
}

// fp32 -> bf16 round-to-nearest-even via bit ops
static __device__ __forceinline__ unsigned short f32_to_bf16_rne(float f) {
    unsigned int u = __float_as_uint(f);
    unsigned int rnd = 0x7FFFu + ((u >> 16) & 1u);
    return (unsigned short)((u + rnd) >> 16);
}

// In-kernel dtype detection: every wave scans the same first 64 shorts of x.
// bf16 N(0,1) data: exponent field never >=133 (|v|>=64). fp32 bits read as
// shorts: even indices are low-mantissa noise, ~48% hits. Threshold 4.
static __device__ __forceinline__ bool inputs_are_fp32(const unsigned short* x16) {
    int lane = threadIdx.x & 63;
    int e = (x16[lane] >> 7) & 0xFF;
    unsigned long long ball = __ballot(e >= 133);
    return __popcll(ball) >= 4;
}

// ---------------------------------------------------------------------------
// Kernel 0: canonical bf16 copies of all 5 inputs (fp32 path only; early-out
// when inputs are already bf16 — consumers then read the raw pointers).
// ---------------------------------------------------------------------------
__global__ __launch_bounds__(256) void convert_all(
    const void* __restrict__ xs, const void* __restrict__ wq,
    const void* __restrict__ wk, const void* __restrict__ wv,
    const void* __restrict__ wo,
    unsigned int* __restrict__ Xc, unsigned int* __restrict__ Wqc,
    unsigned int* __restrict__ Wkc, unsigned int* __restrict__ Wvc,
    unsigned int* __restrict__ Woc)
{
    if (!inputs_are_fp32((const unsigned short*)xs)) return;
    int i = blockIdx.x * 256 + threadIdx.x;  // 0 .. 4194303
    const float* src;
    unsigned int* dst;
    int off;
    if (i < 2097152) { src = (const float*)xs; dst = Xc; off = i; }
    else {
        int j = i - 2097152;
        int t = j >> 19;          // 0..3
        off = j & 524287;
        src = (const float*)((t == 0) ? wq : (t == 1) ? wk : (t == 2) ? wv : wo);
        dst = (t == 0) ? Wqc : (t == 1) ? Wkc : (t == 2) ? Wvc : Woc;
    }
    unsigned int lo = f32_to_bf16_rne(src[2 * off]);
    unsigned int hi = f32_to_bf16_rne(src[2 * off + 1]);
    dst[off] = (hi << 16) | lo;
}

// ---------------------------------------------------------------------------
// Kernel 1: QKV projection GEMM (C = X * W^T) with fused RoPE epilogue.
// Register-prefetch pipeline; V written TRANSPOSED [b,h,d,s] via LDS.
// ---------------------------------------------------------------------------
__global__ __launch_bounds__(256) void gemm_qkv_rope(
    const void* __restrict__ xr,
    const void* __restrict__ wqr, const void* __restrict__ wkr,
    const void* __restrict__ wvr,
    const bf16* __restrict__ Xc,
    const bf16* __restrict__ Wqc, const bf16* __restrict__ Wkc,
    const bf16* __restrict__ Wvc,
    const int* __restrict__ pos,
    bf16* __restrict__ Qb, bf16* __restrict__ Kb, bf16* __restrict__ Vt)
{
    const bool f32in = inputs_are_fp32((const unsigned short*)xr);
    const bf16* X = f32in ? Xc : (const bf16*)xr;

    __shared__ __align__(16) short Xs[64 * 40];
    __shared__ __align__(16) short Ws[64 * 40];
    __shared__ __align__(16) short Ts[64 * 72];   // V transpose staging

    const int m0   = blockIdx.x * 64;
    const int wsel = blockIdx.y >> 4;            // 0=Q, 1=K, 2=V
    const int n0   = (blockIdx.y & 15) * 64;
    const bf16* W  = (wsel == 0) ? (f32in ? Wqc : (const bf16*)wqr)
                   : (wsel == 1) ? (f32in ? Wkc : (const bf16*)wkr)
                                 : (f32in ? Wvc : (const bf16*)wvr);

    const int tid  = threadIdx.x;
    const int lane = tid & 63;
    const int wave = tid >> 6;
    const int wr   = wave >> 1, wc = wave & 1;
    const int srow = tid >> 2;
    const int sseg = tid & 3;
    const int fr   = lane & 15;
    const int fq   = lane >> 4;

    const bf16* Xrow = X + (m0 + srow) * 1024 + sseg * 8;
    const bf16* Wrow = W + (n0 + srow) * 1024 + sseg * 8;

    f32x4 acc00 = {0.f,0.f,0.f,0.f}, acc01 = {0.f,0.f,0.f,0.f};
    f32x4 acc10 = {0.f,0.f,0.f,0.f}, acc11 = {0.f,0.f,0.f,0.f};

    short8 pxa = *(const short8*)(Xrow);   // prefetch k0 = 0
    short8 pwb = *(const short8*)(Wrow);

    for (int k0 = 0; k0 < 1024; k0 += 32) {
        __syncthreads();
        *(short8*)&Xs[srow * 40 + sseg * 8] = pxa;
        *(short8*)&Ws[srow * 40 + sseg * 8] = pwb;
        __syncthreads();
        if (k0 + 32 < 1024) {               // prefetch next tile (overlaps MFMA)
            pxa = *(const short8*)(Xrow + k0 + 32);
            pwb = *(const short8*)(Wrow + k0 + 32);
        }

        short8 a0 = *(const short8*)&Xs[(wr * 32 +      fr) * 40 + fq * 8];
        short8 a1 = *(const short8*)&Xs[(wr * 32 + 16 + fr) * 40 + fq * 8];
        short8 b0 = *(const short8*)&Ws[(wc * 32 +      fr) * 40 + fq * 8];
        short8 b1 = *(const short8*)&Ws[(wc * 32 + 16 + fr) * 40 + fq * 8];
        acc00 = MFMA16(a0, b0, acc00);
        acc01 = MFMA16(a0, b1, acc01);
        acc10 = MFMA16(a1, b0, acc10);
        acc11 = MFMA16(a1, b1, acc11);
    }

    const int bb = m0 >> 11;
    const int s0 = m0 & 2047;
    const int hh = n0 >> 6;

    if (wsel < 2) {
        for (int i = 0; i < 2; ++i)
            for (int j = 0; j < 2; ++j) {
                f32x4 a = (i == 0) ? ((j == 0) ? acc00 : acc01)
                                   : ((j == 0) ? acc10 : acc11);
                for (int r = 0; r < 4; ++r) {
                    int s = s0 + wr * 32 + i * 16 + fq * 4 + r;
                    int d = wc * 32 + j * 16 + fr;
                    float v = a[r];
                    float partner = __shfl_xor(v, 1);
                    int   p    = d >> 1;
                    float freq = __expf((float)p * -0.28782313662425575f);
                    float ang  = (float)pos[s] * freq;
                    float sn, c;
                    sincosf(ang, &sn, &c);
                    float outv = ((d & 1) == 0) ? (c * v - sn * partner)
                                                : (sn * partner + c * v);
                    bf16* dstb = (wsel == 0) ? Qb : Kb;
                    dstb[((bb * 16 + hh) * 2048 + s) * 64 + d] = __float2bfloat16(outv);
                }
            }
    } else {
        for (int i = 0; i < 2; ++i)
            for (int j = 0; j < 2; ++j) {
                f32x4 a = (i == 0) ? ((j == 0) ? acc00 : acc01)
                                   : ((j == 0) ? acc10 : acc11);
                for (int r = 0; r < 4; ++r) {
                    int ls = wr * 32 + i * 16 + fq * 4 + r;   // local s
                    int ld = wc * 32 + j * 16 + fr;           // local d
                    bf16 hv = __float2bfloat16(a[r]);
                    Ts[ld * 72 + ls] = *(short*)&hv;
                }
            }
        __syncthreads();
        int dd = tid >> 2;
        int sc = (tid & 3) * 16;
        short8 t0 = *(const short8*)&Ts[dd * 72 + sc];
        short8 t1 = *(const short8*)&Ts[dd * 72 + sc + 8];
        bf16* vrow = Vt + ((bb * 16 + hh) * 64 + dd) * 2048 + s0 + sc;
        *(short8*)(vrow)     = t0;
        *(short8*)(vrow + 8) = t1;
    }
}

// ---------------------------------------------------------------------------
// Kernel 2: causal flash attention, MFMA bf16, LDS-staged, DPP softmax.
// grid = (16 qt, 16 h, 2 b), block = 256 (4 waves), 128 Q rows per block:
// wave owns 2 x 16-row strips -> K/V fragment LDS reads amortized 2x.
// All 512 blocks co-resident. LDS row stride 72 (free 2-way banks).
// ---------------------------------------------------------------------------
#define FS 72

__global__ __launch_bounds__(256) void flash_attn(
    const bf16* __restrict__ Qb, const bf16* __restrict__ Kb,
    const bf16* __restrict__ Vt, bf16* __restrict__ ctx)
{
    const int qt = 15 - blockIdx.x;   // long blocks dispatch first
    const int h = blockIdx.y, b = blockIdx.z;
    const int bh = b * 16 + h;

    __shared__ __align__(16) short Ks[64 * FS];       // [key][d]
    __shared__ __align__(16) short Vs[64 * FS];       // [d][key]  (V^T tile)
    __shared__ __align__(16) short Ps[4][32 * FS];    // per-wave P (2 strips)

    const int tid  = threadIdx.x;
    const int lane = tid & 63;
    const int wave = tid >> 6;
    const int m = lane & 15;          // fragment row/col
    const int q = lane >> 4;          // quad
    const int srow = tid >> 2;        // staging row 0..63
    const int sseg = tid & 3;         // staging 8-col segment

    // Q fragments for 2 strips: rows qt*128 + wave*32 + t*16 + m
    const bf16* Qp = Qb + (bh * 2048 + qt * 128 + wave * 32 + m) * 64;
    short8 qf[2][2];
    qf[0][0] = *(const short8*)(Qp + q * 8);
    qf[0][1] = *(const short8*)(Qp + 32 + q * 8);
    qf[1][0] = *(const short8*)(Qp + 16 * 64 + q * 8);
    qf[1][1] = *(const short8*)(Qp + 16 * 64 + 32 + q * 8);

    f32x4 oacc[2][4];
    float mi[2][4], li[2][4];
    for (int t = 0; t < 2; ++t)
        for (int nb = 0; nb < 4; ++nb) {
            oacc[t][nb] = (f32x4){0.f, 0.f, 0.f, 0.f};
        }
    for (int t = 0; t < 2; ++t)
        for (int r = 0; r < 4; ++r) { mi[t][r] = NEG_BIG; li[t][r] = 0.f; }

    const bf16* Krow = Kb + bh * 2048 * 64 + srow * 64   + sseg * 8;
    const bf16* Vrow = Vt + bh * 64 * 2048 + srow * 2048 + sseg * 8;

    // prefetch tile 0
    short8 kr0 = *(const short8*)(Krow);
    short8 kr1 = *(const short8*)(Krow + 32);
    short8 vr0 = *(const short8*)(Vrow);
    short8 vr1 = *(const short8*)(Vrow + 32);

    const int ktmax = 2 * qt + 1;
    const int rowbase = qt * 128 + wave * 32;

    for (int kt = 0; kt <= ktmax; ++kt) {
        __syncthreads();  // prior tile's Ks/Vs reads complete
        *(short8*)&Ks[srow * FS + sseg * 8]      = kr0;
        *(short8*)&Ks[srow * FS + sseg * 8 + 32] = kr1;
        *(short8*)&Vs[srow * FS + sseg * 8]      = vr0;
        *(short8*)&Vs[srow * FS + sseg * 8 + 32] = vr1;
        __syncthreads();

        if (kt < ktmax) {   // prefetch next tile; overlaps all compute below
            const bf16* Kn = Krow + (kt + 1) * 4096;
            const bf16* Vn = Vrow + (kt + 1) * 64;
            kr0 = *(const short8*)(Kn);
            kr1 = *(const short8*)(Kn + 32);
            vr0 = *(const short8*)(Vn);
            vr1 = *(const short8*)(Vn + 32);
        }

        // ---- S = Q K^T: K frags read ONCE, used by both strips ----
        f32x4 sacc[2][4];
        for (int nb = 0; nb < 4; ++nb) {
            short8 kf0 = *(const short8*)&Ks[(nb * 16 + m) * FS + q * 8];
            short8 kf1 = *(const short8*)&Ks[(nb * 16 + m) * FS + 32 + q * 8];
            for (int t = 0; t < 2; ++t) {
                f32x4 z = {0.f, 0.f, 0.f, 0.f};
                z = MFMA16(qf[t][0], kf0, z);
                z = MFMA16(qf[t][1], kf1, z);
                sacc[t][nb] = z;
            }
        }

        // ---- scale + causal mask (only on near-diagonal tiles) ----
        for (int t = 0; t < 2; ++t)
            for (int nb = 0; nb < 4; ++nb)
                for (int r = 0; r < 4; ++r)
                    sacc[t][nb][r] *= 0.125f;
        if (kt * 64 + 63 > rowbase) {
            for (int t = 0; t < 2; ++t)
                for (int nb = 0; nb < 4; ++nb)
                    for (int r = 0; r < 4; ++r) {
                        int row = rowbase + t * 16 + q * 4 + r;
                        int col = kt * 64 + nb * 16 + m;
                        if (col > row) sacc[t][nb][r] = NEG_BIG;
                    }
        }

        // ---- online softmax: DPP row reductions (VALU pipe, no LDS) ----
        for (int t = 0; t < 2; ++t) {
            float mnew[4], alpha[4];
            for (int r = 0; r < 4; ++r) {
                float rm = fmaxf(fmaxf(sacc[t][0][r], sacc[t][1][r]),
                                 fmaxf(sacc[t][2][r], sacc[t][3][r]));
                rm = rowmax16(rm);
                mnew[r]  = fmaxf(mi[t][r], rm);
                alpha[r] = __expf(fmaxf(mi[t][r] - mnew[r], -80.f));
                mi[t][r] = mnew[r];
            }
            for (int r = 0; r < 4; ++r) {
                float acc = 0.f;
                for (int nb = 0; nb < 4; ++nb) {
                    float p = __expf(fmaxf(sacc[t][nb][r] - mnew[r], -80.f));
                    sacc[t][nb][r] = p;
                    acc += p;
                }
                acc = rowsum16(acc);
                li[t][r] = li[t][r] * alpha[r] + acc;
                for (int nb = 0; nb < 4; ++nb) oacc[t][nb][r] *= alpha[r];
            }
        }

        // ---- P (C layout) -> wave-private LDS -> A-frag layout ----
        for (int t = 0; t < 2; ++t)
            for (int nb = 0; nb < 4; ++nb)
                for (int r = 0; r < 4; ++r) {
                    bf16 hv = __float2bfloat16(sacc[t][nb][r]);
                    Ps[wave][(t * 16 + q * 4 + r) * FS + nb * 16 + m] = *(short*)&hv;
                }
        short8 pa[2][2];
        for (int t = 0; t < 2; ++t) {
            pa[t][0] = *(const short8*)&Ps[wave][(t * 16 + m) * FS + q * 8];
            pa[t][1] = *(const short8*)&Ps[wave][(t * 16 + m) * FS + 32 + q * 8];
        }

        // ---- O += P V: V frags read ONCE, used by both strips ----
        for (int nb = 0; nb < 4; ++nb) {
            short8 vf0 = *(const short8*)&Vs[(nb * 16 + m) * FS + q * 8];
            short8 vf1 = *(const short8*)&Vs[(nb * 16 + m) * FS + 32 + q * 8];
            for (int t = 0; t < 2; ++t) {
                oacc[t][nb] = MFMA16(pa[t][0], vf0, oacc[t][nb]);
                oacc[t][nb] = MFMA16(pa[t][1], vf1, oacc[t][nb]);
            }
        }
    }

    // ---- normalize + write ctx [b, s, h*64+d] ----
    for (int t = 0; t < 2; ++t)
        for (int r = 0; r < 4; ++r) {
            float inv = 1.f / li[t][r];
            int srowg = qt * 128 + wave * 32 + t * 16 + q * 4 + r;
            for (int nb = 0; nb < 4; ++nb)
                ctx[(b * 2048 + srowg) * 1024 + h * 64 + nb * 16 + m] =
                    __float2bfloat16(oacc[t][nb][r] * inv);
        }
}

// ---------------------------------------------------------------------------
// Kernel 3: output projection (out = ctx * Wo^T), prefetch pipeline.
// ---------------------------------------------------------------------------
__global__ __launch_bounds__(256) void gemm_out(
    const bf16* __restrict__ A,
    const void* __restrict__ wor, const bf16* __restrict__ Woc,
    const void* __restrict__ xr,
    void* __restrict__ out)
{
    const bool f32in = inputs_are_fp32((const unsigned short*)xr);
    const bf16* W = f32in ? Woc : (const bf16*)wor;

    __shared__ __align__(16) short As[64 * 40];
    __shared__ __align__(16) short Ws[64 * 40];

    const int m0 = blockIdx.x * 64;
    const int n0 = blockIdx.y * 64;
    const int tid  = threadIdx.x;
    const int lane = tid & 63;
    const int wave = tid >> 6;
    const int wr = wave >> 1, wc = wave & 1;
    const int srow = tid >> 2, sseg = tid & 3;
    const int fr = lane & 15, fq = lane >> 4;

    const bf16* Arow = A + (m0 + srow) * 1024 + sseg * 8;
    const bf16* Wrow = W + (n0 + srow) * 1024 + sseg * 8;

    f32x4 acc00 = {0.f,0.f,0.f,0.f}, acc01 = {0.f,0.f,0.f,0.f};
    f32x4 acc10 = {0.f,0.f,0.f,0.f}, acc11 = {0.f,0.f,0.f,0.f};

    short8 paa = *(const short8*)(Arow);
    short8 pwb = *(const short8*)(Wrow);

    for (int k0 = 0; k0 < 1024; k0 += 32) {
        __syncthreads();
        *(short8*)&As[srow * 40 + sseg * 8] = paa;
        *(short8*)&Ws[srow * 40 + sseg * 8] = pwb;
        __syncthreads();
        if (k0 + 32 < 1024) {
            paa = *(const short8*)(Arow + k0 + 32);
            pwb = *(const short8*)(Wrow + k0 + 32);
        }
        short8 a0 = *(const short8*)&As[(wr * 32 +      fr) * 40 + fq * 8];
        short8 a1 = *(const short8*)&As[(wr * 32 + 16 + fr) * 40 + fq * 8];
        short8 b0 = *(const short8*)&Ws[(wc * 32 +      fr) * 40 + fq * 8];
        short8 b1 = *(const short8*)&Ws[(wc * 32 + 16 + fr) * 40 + fq * 8];
        acc00 = MFMA16(a0, b0, acc00);
        acc01 = MFMA16(a0, b1, acc01);
        acc10 = MFMA16(a1, b0, acc10);
        acc11 = MFMA16(a1, b1, acc11);
    }

    for (int i = 0; i < 2; ++i)
        for (int j = 0; j < 2; ++j) {
            f32x4 a = (i == 0) ? ((j == 0) ? acc00 : acc01)
                               : ((j == 0) ? acc10 : acc11);
            for (int r = 0; r < 4; ++r) {
                int gm = m0 + wr * 32 + i * 16 + fq * 4 + r;
                int gn = n0 + wc * 32 + j * 16 + fr;
                int idx = gm * 1024 + gn;
                if (f32in) ((float*)out)[idx] = a[r];
                else       ((bf16*)out)[idx]  = __float2bfloat16(a[r]);
            }
        }
}

// ---------------------------------------------------------------------------
extern "C" void kernel_launch(void* const* d_in, const int* in_sizes, int n_in,
                              void* d_out, int out_size, void* d_ws, size_t ws_size,
                              hipStream_t stream)
{
    const void* x_raw  = d_in[0];
    const void* Wq_raw = d_in[1];
    const void* Wk_raw = d_in[2];
    const void* Wv_raw = d_in[3];
    const void* Wo_raw = d_in[4];
    const int*  pos    = (const int*)d_in[5];

    char* ws = (char*)d_ws;
    bf16* Xc  = (bf16*)ws;                                    // 8 MB
    bf16* Wqc = (bf16*)(ws + 8388608);                        // 2 MB each
    bf16* Wkc = (bf16*)(ws + 8388608 + 2097152);
    bf16* Wvc = (bf16*)(ws + 8388608 + 2 * 2097152);
    bf16* Woc = (bf16*)(ws + 8388608 + 3 * 2097152);
    bf16* Qb  = (bf16*)(ws + 8388608 + 4 * 2097152);          // 8 MB each
    bf16* Kb  = Qb + 4194304;
    bf16* Vt  = Kb + 4194304;
    bf16* ctx = Vt + 4194304;

    convert_all<<<16384, 256, 0, stream>>>(
        x_raw, Wq_raw, Wk_raw, Wv_raw, Wo_raw,
        (unsigned int*)Xc, (unsigned int*)Wqc, (unsigned int*)Wkc,
        (unsigned int*)Wvc, (unsigned int*)Woc);

    gemm_qkv_rope<<<dim3(64, 48), 256, 0, stream>>>(
        x_raw, Wq_raw, Wk_raw, Wv_raw, Xc, Wqc, Wkc, Wvc, pos, Qb, Kb, Vt);
    flash_attn<<<dim3(16, 16, 2), 256, 0, stream>>>(Qb, Kb, Vt, ctx);
    gemm_out<<<dim3(64, 16), 256, 0, stream>>>(ctx, Wo_raw, Woc, x_raw, d_out);
}

// Round 10
// 220.157 us; speedup vs baseline: 1.7868x; 1.2068x over previous
//
#include <hip/hip_runtime.h>
#include <hip/hip_bf16.h>
#include <math.h>

typedef __hip_bfloat16 bf16;
typedef __attribute__((ext_vector_type(8))) short short8;
typedef __attribute__((ext_vector_type(4))) float f32x4;

#define MFMA16(A, B, C) __builtin_amdgcn_mfma_f32_16x16x32_bf16((A), (B), (C), 0, 0, 0)
#define NEG_BIG (-1e30f)

// DPP row_ror rotate within 16-lane rows (VALU pipe — NOT LDS, unlike __shfl)
#define DPP_F(x, ctrl) \
    __int_as_float(__builtin_amdgcn_update_dpp(0, __float_as_int(x), (ctrl), 0xf, 0xf, false))

static __device__ __forceinline__ float rowsum16(float x) {
    x += DPP_F(x, 0x121);   // ror:1
    x += DPP_F(x, 0x122);   // ror:2
    x += DPP_F(x, 0x124);   // ror:4
    x += DPP_F(x, 0x128);   // ror:8
    return x;
}
static __device__ __forceinline__ float rowmax16(float x) {
    x = fmaxf(x, DPP_F(x, 0x121));
    x = fmaxf(x, DPP_F(x, 0x122));
    x = fmaxf(x, DPP_F(x, 0x124));
    x = fmaxf(x, DPP_F(x, 0x128));
    return x;
}

// fp32 -> bf16 round-to-nearest-even via bit ops
static __device__ __forceinline__ unsigned short f32_to_bf16_rne(float f) {
    unsigned int u = __float_as_uint(f);
    unsigned int rnd = 0x7FFFu + ((u >> 16) & 1u);
    return (unsigned short)((u + rnd) >> 16);
}

// In-kernel dtype detection (wave-uniform): scan first 64 shorts of x.
static __device__ __forceinline__ bool inputs_are_fp32(const unsigned short* x16) {
    int lane = threadIdx.x & 63;
    int e = (x16[lane] >> 7) & 0xFF;
    unsigned long long ball = __ballot(e >= 133);
    return __popcll(ball) >= 4;
}

// ---------------------------------------------------------------------------
// Kernel 0: canonical bf16 copies of all 5 inputs (fp32 path only).
// ---------------------------------------------------------------------------
__global__ __launch_bounds__(256) void convert_all(
    const void* __restrict__ xs, const void* __restrict__ wq,
    const void* __restrict__ wk, const void* __restrict__ wv,
    const void* __restrict__ wo,
    unsigned int* __restrict__ Xc, unsigned int* __restrict__ Wqc,
    unsigned int* __restrict__ Wkc, unsigned int* __restrict__ Wvc,
    unsigned int* __restrict__ Woc)
{
    if (!inputs_are_fp32((const unsigned short*)xs)) return;
    int i = blockIdx.x * 256 + threadIdx.x;  // 0 .. 4194303
    const float* src;
    unsigned int* dst;
    int off;
    if (i < 2097152) { src = (const float*)xs; dst = Xc; off = i; }
    else {
        int j = i - 2097152;
        int t = j >> 19;          // 0..3
        off = j & 524287;
        src = (const float*)((t == 0) ? wq : (t == 1) ? wk : (t == 2) ? wv : wo);
        dst = (t == 0) ? Wqc : (t == 1) ? Wkc : (t == 2) ? Wvc : Woc;
    }
    unsigned int lo = f32_to_bf16_rne(src[2 * off]);
    unsigned int hi = f32_to_bf16_rne(src[2 * off + 1]);
    dst[off] = (hi << 16) | lo;
}

// ---------------------------------------------------------------------------
// Kernel 1: QKV projection GEMM (C = X * W^T) with fused RoPE epilogue.
// Register-prefetch pipeline; V written TRANSPOSED [b,h,d,s] via LDS.
// ---------------------------------------------------------------------------
__global__ __launch_bounds__(256) void gemm_qkv_rope(
    const void* __restrict__ xr,
    const void* __restrict__ wqr, const void* __restrict__ wkr,
    const void* __restrict__ wvr,
    const bf16* __restrict__ Xc,
    const bf16* __restrict__ Wqc, const bf16* __restrict__ Wkc,
    const bf16* __restrict__ Wvc,
    const int* __restrict__ pos,
    bf16* __restrict__ Qb, bf16* __restrict__ Kb, bf16* __restrict__ Vt)
{
    const bool f32in = inputs_are_fp32((const unsigned short*)xr);
    const bf16* X = f32in ? Xc : (const bf16*)xr;

    __shared__ __align__(16) short Xs[64 * 40];
    __shared__ __align__(16) short Ws[64 * 40];
    __shared__ __align__(16) short Ts[64 * 72];   // V transpose staging

    const int m0   = blockIdx.x * 64;
    const int wsel = blockIdx.y >> 4;            // 0=Q, 1=K, 2=V
    const int n0   = (blockIdx.y & 15) * 64;
    const bf16* W  = (wsel == 0) ? (f32in ? Wqc : (const bf16*)wqr)
                   : (wsel == 1) ? (f32in ? Wkc : (const bf16*)wkr)
                                 : (f32in ? Wvc : (const bf16*)wvr);

    const int tid  = threadIdx.x;
    const int lane = tid & 63;
    const int wave = tid >> 6;
    const int wr   = wave >> 1, wc = wave & 1;
    const int srow = tid >> 2;
    const int sseg = tid & 3;
    const int fr   = lane & 15;
    const int fq   = lane >> 4;

    const bf16* Xrow = X + (m0 + srow) * 1024 + sseg * 8;
    const bf16* Wrow = W + (n0 + srow) * 1024 + sseg * 8;

    f32x4 acc00 = {0.f,0.f,0.f,0.f}, acc01 = {0.f,0.f,0.f,0.f};
    f32x4 acc10 = {0.f,0.f,0.f,0.f}, acc11 = {0.f,0.f,0.f,0.f};

    short8 pxa = *(const short8*)(Xrow);   // prefetch k0 = 0
    short8 pwb = *(const short8*)(Wrow);

    for (int k0 = 0; k0 < 1024; k0 += 32) {
        __syncthreads();
        *(short8*)&Xs[srow * 40 + sseg * 8] = pxa;
        *(short8*)&Ws[srow * 40 + sseg * 8] = pwb;
        __syncthreads();
        if (k0 + 32 < 1024) {               // prefetch next tile (overlaps MFMA)
            pxa = *(const short8*)(Xrow + k0 + 32);
            pwb = *(const short8*)(Wrow + k0 + 32);
        }

        short8 a0 = *(const short8*)&Xs[(wr * 32 +      fr) * 40 + fq * 8];
        short8 a1 = *(const short8*)&Xs[(wr * 32 + 16 + fr) * 40 + fq * 8];
        short8 b0 = *(const short8*)&Ws[(wc * 32 +      fr) * 40 + fq * 8];
        short8 b1 = *(const short8*)&Ws[(wc * 32 + 16 + fr) * 40 + fq * 8];
        acc00 = MFMA16(a0, b0, acc00);
        acc01 = MFMA16(a0, b1, acc01);
        acc10 = MFMA16(a1, b0, acc10);
        acc11 = MFMA16(a1, b1, acc11);
    }

    const int bb = m0 >> 11;
    const int s0 = m0 & 2047;
    const int hh = n0 >> 6;

    if (wsel < 2) {
        for (int i = 0; i < 2; ++i)
            for (int j = 0; j < 2; ++j) {
                f32x4 a = (i == 0) ? ((j == 0) ? acc00 : acc01)
                                   : ((j == 0) ? acc10 : acc11);
                for (int r = 0; r < 4; ++r) {
                    int s = s0 + wr * 32 + i * 16 + fq * 4 + r;
                    int d = wc * 32 + j * 16 + fr;
                    float v = a[r];
                    float partner = __shfl_xor(v, 1);
                    int   p    = d >> 1;
                    float freq = __expf((float)p * -0.28782313662425575f);
                    float ang  = (float)pos[s] * freq;
                    float sn, c;
                    sincosf(ang, &sn, &c);
                    float outv = ((d & 1) == 0) ? (c * v - sn * partner)
                                                : (sn * partner + c * v);
                    bf16* dstb = (wsel == 0) ? Qb : Kb;
                    dstb[((bb * 16 + hh) * 2048 + s) * 64 + d] = __float2bfloat16(outv);
                }
            }
    } else {
        for (int i = 0; i < 2; ++i)
            for (int j = 0; j < 2; ++j) {
                f32x4 a = (i == 0) ? ((j == 0) ? acc00 : acc01)
                                   : ((j == 0) ? acc10 : acc11);
                for (int r = 0; r < 4; ++r) {
                    int ls = wr * 32 + i * 16 + fq * 4 + r;   // local s
                    int ld = wc * 32 + j * 16 + fr;           // local d
                    bf16 hv = __float2bfloat16(a[r]);
                    Ts[ld * 72 + ls] = *(short*)&hv;
                }
            }
        __syncthreads();
        int dd = tid >> 2;
        int sc = (tid & 3) * 16;
        short8 t0 = *(const short8*)&Ts[dd * 72 + sc];
        short8 t1 = *(const short8*)&Ts[dd * 72 + sc + 8];
        bf16* vrow = Vt + ((bb * 16 + hh) * 64 + dd) * 2048 + s0 + sc;
        *(short8*)(vrow)     = t0;
        *(short8*)(vrow + 8) = t1;
    }
}

// ---------------------------------------------------------------------------
// Kernel 2: causal flash attention, MFMA bf16, BALANCED pairs + 128-key
// double-tiles. grid = (16 pairs, 16 h, 2 b), block = 256 (4 waves).
// Block processes Q-tile `pair` then Q-tile `31-pair` (64 rows each):
// staged double-iters = (pair+2)/2 + (33-pair)/2 = 17 for EVERY block.
// Strides: Ks 72, Vs/Ps 136 shorts (both = 4 dwords mod 32 -> free 2-way).
// ---------------------------------------------------------------------------
#define KST 72
#define VST 136

__global__ __launch_bounds__(256) void flash_attn(
    const bf16* __restrict__ Qb, const bf16* __restrict__ Kb,
    const bf16* __restrict__ Vt, bf16* __restrict__ ctx)
{
    const int pair = blockIdx.x;      // 0..15
    const int h = blockIdx.y, b = blockIdx.z;
    const int bh = b * 16 + h;

    __shared__ __align__(16) short Ks[128 * KST];     // [key 0..127][d]
    __shared__ __align__(16) short Vs[64 * VST];      // [d][key 0..127]
    __shared__ __align__(16) short Ps[4][16 * VST];   // per-wave P [row][key]

    const int tid  = threadIdx.x;
    const int lane = tid & 63;
    const int wave = tid >> 6;
    const int m = lane & 15;          // fragment row/col
    const int q = lane >> 4;          // quad

    // staging indices
    const int krow = tid >> 1;            // 0..127
    const int kseg = (tid & 1) * 32;      // 0 / 32
    const int vrow = tid >> 2;            // 0..63
    const int vseg = (tid & 3) * 32;      // 0..96

    const bf16* Kg = Kb + bh * 2048 * 64 + krow * 64   + kseg;  // + kt2*8192
    const bf16* Vg = Vt + bh * 64 * 2048 + vrow * 2048 + vseg;  // + kt2*128

    for (int part = 0; part < 2; ++part) {
        const int qtile = (part == 0) ? pair : 31 - pair;   // 64-row Q tile
        const int nk2 = (qtile + 2) >> 1;                   // 128-key iters
        const int rowbase = qtile * 64 + wave * 16;

        // Q fragments: rows qtile*64 + wave*16 + m
        const bf16* Qp = Qb + (bh * 2048 + qtile * 64 + wave * 16 + m) * 64;
        short8 qf0 = *(const short8*)(Qp + q * 8);
        short8 qf1 = *(const short8*)(Qp + 32 + q * 8);

        f32x4 oacc[4];
        for (int nb = 0; nb < 4; ++nb) oacc[nb] = (f32x4){0.f, 0.f, 0.f, 0.f};
        float mi[4], li[4];
        for (int r = 0; r < 4; ++r) { mi[r] = NEG_BIG; li[r] = 0.f; }

        // prefetch double-tile 0
        short8 kr[4], vr[4];
        for (int j = 0; j < 4; ++j) {
            kr[j] = *(const short8*)(Kg + j * 8);
            vr[j] = *(const short8*)(Vg + j * 8);
        }

        for (int kt2 = 0; kt2 < nk2; ++kt2) {
            __syncthreads();  // prior iter's Ks/Vs reads complete
            for (int j = 0; j < 4; ++j) {
                *(short8*)&Ks[krow * KST + kseg + j * 8] = kr[j];
                *(short8*)&Vs[vrow * VST + vseg + j * 8] = vr[j];
            }
            __syncthreads();

            if (kt2 + 1 < nk2) {   // prefetch next double-tile
                for (int j = 0; j < 4; ++j) {
                    kr[j] = *(const short8*)(Kg + (kt2 + 1) * 8192 + j * 8);
                    vr[j] = *(const short8*)(Vg + (kt2 + 1) * 128  + j * 8);
                }
            }

            // ---- S = Q K^T over 8 col-blocks of 16 keys ----
            f32x4 sacc[8];
            for (int nc = 0; nc < 8; ++nc) {
                short8 kf0 = *(const short8*)&Ks[(nc * 16 + m) * KST + q * 8];
                short8 kf1 = *(const short8*)&Ks[(nc * 16 + m) * KST + 32 + q * 8];
                f32x4 z = {0.f, 0.f, 0.f, 0.f};
                z = MFMA16(qf0, kf0, z);
                z = MFMA16(qf1, kf1, z);
                sacc[nc] = z;
            }

            // ---- scale (+ causal mask near diagonal; overhang keys masked) ----
            for (int nc = 0; nc < 8; ++nc)
                for (int r = 0; r < 4; ++r)
                    sacc[nc][r] *= 0.125f;
            if (kt2 * 128 + 127 > rowbase) {
                for (int nc = 0; nc < 8; ++nc)
                    for (int r = 0; r < 4; ++r) {
                        int row = rowbase + q * 4 + r;
                        int col = kt2 * 128 + nc * 16 + m;
                        if (col > row) sacc[nc][r] = NEG_BIG;
                    }
            }

            // ---- online softmax (DPP row reductions, VALU pipe) ----
            float mnew[4], alpha[4];
            for (int r = 0; r < 4; ++r) {
                float rm = sacc[0][r];
                for (int nc = 1; nc < 8; ++nc) rm = fmaxf(rm, sacc[nc][r]);
                rm = rowmax16(rm);
                mnew[r]  = fmaxf(mi[r], rm);
                alpha[r] = __expf(fmaxf(mi[r] - mnew[r], -80.f));
                mi[r]    = mnew[r];
            }
            for (int r = 0; r < 4; ++r) {
                float acc = 0.f;
                for (int nc = 0; nc < 8; ++nc) {
                    float p = __expf(fmaxf(sacc[nc][r] - mnew[r], -80.f));
                    sacc[nc][r] = p;
                    acc += p;
                }
                acc = rowsum16(acc);
                li[r] = li[r] * alpha[r] + acc;
                for (int nb = 0; nb < 4; ++nb) oacc[nb][r] *= alpha[r];
            }

            // ---- P (C layout) -> wave-private LDS -> A-frag layout ----
            for (int nc = 0; nc < 8; ++nc)
                for (int r = 0; r < 4; ++r) {
                    bf16 hv = __float2bfloat16(sacc[nc][r]);
                    Ps[wave][(q * 4 + r) * VST + nc * 16 + m] = *(short*)&hv;
                }
            short8 pa[4];
            for (int ck = 0; ck < 4; ++ck)
                pa[ck] = *(const short8*)&Ps[wave][m * VST + ck * 32 + q * 8];

            // ---- O += P V over 4 key-chunks of 32 ----
            for (int nb = 0; nb < 4; ++nb) {
                for (int ck = 0; ck < 4; ++ck) {
                    short8 vf = *(const short8*)&Vs[(nb * 16 + m) * VST + ck * 32 + q * 8];
                    oacc[nb] = MFMA16(pa[ck], vf, oacc[nb]);
                }
            }
        }

        // ---- normalize + write ctx [b, s, h*64+d] ----
        for (int r = 0; r < 4; ++r) {
            float inv = 1.f / li[r];
            int srowg = qtile * 64 + wave * 16 + q * 4 + r;
            for (int nb = 0; nb < 4; ++nb)
                ctx[(b * 2048 + srowg) * 1024 + h * 64 + nb * 16 + m] =
                    __float2bfloat16(oacc[nb][r] * inv);
        }
        __syncthreads();  // part A's LDS reads done before part B restages
    }
}

// ---------------------------------------------------------------------------
// Kernel 3: output projection (out = ctx * Wo^T), prefetch pipeline.
// ---------------------------------------------------------------------------
__global__ __launch_bounds__(256) void gemm_out(
    const bf16* __restrict__ A,
    const void* __restrict__ wor, const bf16* __restrict__ Woc,
    const void* __restrict__ xr,
    void* __restrict__ out)
{
    const bool f32in = inputs_are_fp32((const unsigned short*)xr);
    const bf16* W = f32in ? Woc : (const bf16*)wor;

    __shared__ __align__(16) short As[64 * 40];
    __shared__ __align__(16) short Ws[64 * 40];

    const int m0 = blockIdx.x * 64;
    const int n0 = blockIdx.y * 64;
    const int tid  = threadIdx.x;
    const int lane = tid & 63;
    const int wave = tid >> 6;
    const int wr = wave >> 1, wc = wave & 1;
    const int srow = tid >> 2, sseg = tid & 3;
    const int fr = lane & 15, fq = lane >> 4;

    const bf16* Arow = A + (m0 + srow) * 1024 + sseg * 8;
    const bf16* Wrow = W + (n0 + srow) * 1024 + sseg * 8;

    f32x4 acc00 = {0.f,0.f,0.f,0.f}, acc01 = {0.f,0.f,0.f,0.f};
    f32x4 acc10 = {0.f,0.f,0.f,0.f}, acc11 = {0.f,0.f,0.f,0.f};

    short8 paa = *(const short8*)(Arow);
    short8 pwb = *(const short8*)(Wrow);

    for (int k0 = 0; k0 < 1024; k0 += 32) {
        __syncthreads();
        *(short8*)&As[srow * 40 + sseg * 8] = paa;
        *(short8*)&Ws[srow * 40 + sseg * 8] = pwb;
        __syncthreads();
        if (k0 + 32 < 1024) {
            paa = *(const short8*)(Arow + k0 + 32);
            pwb = *(const short8*)(Wrow + k0 + 32);
        }
        short8 a0 = *(const short8*)&As[(wr * 32 +      fr) * 40 + fq * 8];
        short8 a1 = *(const short8*)&As[(wr * 32 + 16 + fr) * 40 + fq * 8];
        short8 b0 = *(const short8*)&Ws[(wc * 32 +      fr) * 40 + fq * 8];
        short8 b1 = *(const short8*)&Ws[(wc * 32 + 16 + fr) * 40 + fq * 8];
        acc00 = MFMA16(a0, b0, acc00);
        acc01 = MFMA16(a0, b1, acc01);
        acc10 = MFMA16(a1, b0, acc10);
        acc11 = MFMA16(a1, b1, acc11);
    }

    for (int i = 0; i < 2; ++i)
        for (int j = 0; j < 2; ++j) {
            f32x4 a = (i == 0) ? ((j == 0) ? acc00 : acc01)
                               : ((j == 0) ? acc10 : acc11);
            for (int r = 0; r < 4; ++r) {
                int gm = m0 + wr * 32 + i * 16 + fq * 4 + r;
                int gn = n0 + wc * 32 + j * 16 + fr;
                int idx = gm * 1024 + gn;
                if (f32in) ((float*)out)[idx] = a[r];
                else       ((bf16*)out)[idx]  = __float2bfloat16(a[r]);
            }
        }
}

// ---------------------------------------------------------------------------
extern "C" void kernel_launch(void* const* d_in, const int* in_sizes, int n_in,
                              void* d_out, int out_size, void* d_ws, size_t ws_size,
                              hipStream_t stream)
{
    const void* x_raw  = d_in[0];
    const void* Wq_raw = d_in[1];
    const void* Wk_raw = d_in[2];
    const void* Wv_raw = d_in[3];
    const void* Wo_raw = d_in[4];
    const int*  pos    = (const int*)d_in[5];

    char* ws = (char*)d_ws;
    bf16* Xc  = (bf16*)ws;                                    // 8 MB
    bf16* Wqc = (bf16*)(ws + 8388608);                        // 2 MB each
    bf16* Wkc = (bf16*)(ws + 8388608 + 2097152);
    bf16* Wvc = (bf16*)(ws + 8388608 + 2 * 2097152);
    bf16* Woc = (bf16*)(ws + 8388608 + 3 * 2097152);
    bf16* Qb  = (bf16*)(ws + 8388608 + 4 * 2097152);          // 8 MB each
    bf16* Kb  = Qb + 4194304;
    bf16* Vt  = Kb + 4194304;
    bf16* ctx = Vt + 4194304;

    convert_all<<<16384, 256, 0, stream>>>(
        x_raw, Wq_raw, Wk_raw, Wv_raw, Wo_raw,
        (unsigned int*)Xc, (unsigned int*)Wqc, (unsigned int*)Wkc,
        (unsigned int*)Wvc, (unsigned int*)Woc);

    gemm_qkv_rope<<<dim3(64, 48), 256, 0, stream>>>(
        x_raw, Wq_raw, Wk_raw, Wv_raw, Xc, Wqc, Wkc, Wvc, pos, Qb, Kb, Vt);
    flash_attn<<<dim3(16, 16, 2), 256, 0, stream>>>(Qb, Kb, Vt, ctx);
    gemm_out<<<dim3(64, 16), 256, 0, stream>>>(ctx, Wo_raw, Woc, x_raw, d_out);
}